// Round 4
// baseline (234.656 us; speedup 1.0000x reference)
//
#include <hip/hip_runtime.h>
#include <math.h>

#define HW   128
#define BH   8           // band height (rows per thread)
#define C_CH 256

__device__ __forceinline__ void sig_tanh(float s, float& fg, float& th) {
    float sc = fminf(15.f, fmaxf(-15.f, s));
    float t  = __expf(-sc);                               // e^-s
    fg = __builtin_amdgcn_rcpf(1.f + t);                  // sigmoid
    float t2 = t * t;                                     // e^-2s
    th = (1.f - t2) * __builtin_amdgcn_rcpf(1.f + t2);    // tanh
}

__device__ __forceinline__ float tanh_fast(float s) {
    float sc = fminf(15.f, fmaxf(-15.f, s));
    float t2 = __expf(-2.f * sc);
    return (1.f - t2) * __builtin_amdgcn_rcpf(1.f + t2);
}

// accumulate one stencil row (weights w0,w1,w2) over a 10-wide row {l, a, b, r}
__device__ __forceinline__ void row_acc(float w0, float w1, float w2,
    float l, const float4& a, const float4& b, float r,
    float4& s0, float4& s1)
{
    s0.x = fmaf(w0, l,   fmaf(w1, a.x, fmaf(w2, a.y, s0.x)));
    s0.y = fmaf(w0, a.x, fmaf(w1, a.y, fmaf(w2, a.z, s0.y)));
    s0.z = fmaf(w0, a.y, fmaf(w1, a.z, fmaf(w2, a.w, s0.z)));
    s0.w = fmaf(w0, a.z, fmaf(w1, a.w, fmaf(w2, b.x, s0.w)));
    s1.x = fmaf(w0, a.w, fmaf(w1, b.x, fmaf(w2, b.y, s1.x)));
    s1.y = fmaf(w0, b.x, fmaf(w1, b.y, fmaf(w2, b.z, s1.y)));
    s1.z = fmaf(w0, b.y, fmaf(w1, b.z, fmaf(w2, b.w, s1.z)));
    s1.w = fmaf(w0, b.z, fmaf(w1, b.w, fmaf(w2, r,   s1.w)));
}

__global__ __launch_bounds__(256, 8) void fused_gated_dwconv_reg(
    const float* __restrict__ x, const float* __restrict__ y,
    const float* __restrict__ w, const float* __restrict__ b,
    float* __restrict__ out)
{
    const int tid   = threadIdx.x;
    const int s     = tid & 15;          // col strip (8 cols each)
    const int band  = tid >> 4;          // 16 bands of 8 rows
    const int plane = blockIdx.x;        // one plane per block
    const int c     = plane & (C_CH - 1);
    const int rb    = band * BH;
    const int col0  = s * 8;

    const size_t poff = (size_t)plane * (HW * HW);
    const float* yp = y + poff + col0;
    const float* xp = x + poff + col0;
    float*       op = out + poff + col0;

    float wk[9];
    #pragma unroll
    for (int k = 0; k < 9; ++k) wk[k] = w[c * 9 + k];
    const float bias = b[c];

    // rolling 3-row windows (10 wide: left halo, 8 cols, right halo)
    float  yl[3], yr[3];  float4 ya[3], yb[3];
    float  xl[3], xr[3];  float4 xa[3], xb[3];
    float4 fa[2], fb[2];  // f_gate, 2-row window

    #pragma unroll
    for (int t = 0; t < BH + 4; ++t) {
        // ---- load y row (rb-2+t) into slot t%3, with shuffle halo ----
        {
            int gy = rb - 2 + t;
            bool iny = (unsigned)gy < (unsigned)HW;
            const float* p = yp + (size_t)(iny ? gy : 0) * HW;
            float4 a  = *reinterpret_cast<const float4*>(p);
            float4 bb = *reinterpret_cast<const float4*>(p + 4);
            if (!iny) { a = make_float4(0.f,0.f,0.f,0.f); bb = make_float4(0.f,0.f,0.f,0.f); }
            float l = __shfl_up(bb.w, 1, 16);  if (s == 0)  l = 0.f;
            float r = __shfl_down(a.x, 1, 16); if (s == 15) r = 0.f;
            const int sl = t % 3;
            yl[sl] = l; ya[sl] = a; yb[sl] = bb; yr[sl] = r;
        }
        // ---- compute x_stage row (qx = rb-3+t) into slot t%3 ----
        if (t >= 2) {
            int qx = rb - 3 + t;
            bool inx = (unsigned)qx < (unsigned)HW;
            const float* p = xp + (size_t)(inx ? qx : 0) * HW;
            float4 xva = *reinterpret_cast<const float4*>(p);
            float4 xvb = *reinterpret_cast<const float4*>(p + 4);

            const int i0 = (t - 2) % 3, i1 = (t - 1) % 3, i2 = t % 3;
            float4 s0 = make_float4(bias, bias, bias, bias), s1 = s0;
            row_acc(wk[0], wk[1], wk[2], yl[i0], ya[i0], yb[i0], yr[i0], s0, s1);
            row_acc(wk[3], wk[4], wk[5], yl[i1], ya[i1], yb[i1], yr[i1], s0, s1);
            row_acc(wk[6], wk[7], wk[8], yl[i2], ya[i2], yb[i2], yr[i2], s0, s1);

            float4 fga, fgb, tha, thb;
            sig_tanh(s0.x, fga.x, tha.x);
            sig_tanh(s0.y, fga.y, tha.y);
            sig_tanh(s0.z, fga.z, tha.z);
            sig_tanh(s0.w, fga.w, tha.w);
            sig_tanh(s1.x, fgb.x, thb.x);
            sig_tanh(s1.y, fgb.y, thb.y);
            sig_tanh(s1.z, fgb.z, thb.z);
            sig_tanh(s1.w, fgb.w, thb.w);

            float4 xsa, xsb;
            xsa.x = fga.x * (xva.x + tha.x);
            xsa.y = fga.y * (xva.y + tha.y);
            xsa.z = fga.z * (xva.z + tha.z);
            xsa.w = fga.w * (xva.w + tha.w);
            xsb.x = fgb.x * (xvb.x + thb.x);
            xsb.y = fgb.y * (xvb.y + thb.y);
            xsb.z = fgb.z * (xvb.z + thb.z);
            xsb.w = fgb.w * (xvb.w + thb.w);
            if (!inx) { xsa = make_float4(0.f,0.f,0.f,0.f); xsb = make_float4(0.f,0.f,0.f,0.f); }

            float l = __shfl_up(xsb.w, 1, 16);  if (s == 0)  l = 0.f;
            float r = __shfl_down(xsa.x, 1, 16); if (s == 15) r = 0.f;
            xl[i2] = l; xa[i2] = xsa; xb[i2] = xsb; xr[i2] = r;
            fa[t & 1] = fga; fb[t & 1] = fgb;
        }
        // ---- output row r = rb-4+t ----
        if (t >= 4) {
            int r = rb - 4 + t;
            const int i0 = (t - 2) % 3, i1 = (t - 1) % 3, i2 = t % 3;
            float4 s0 = make_float4(bias, bias, bias, bias), s1 = s0;
            row_acc(wk[0], wk[1], wk[2], xl[i0], xa[i0], xb[i0], xr[i0], s0, s1);
            row_acc(wk[3], wk[4], wk[5], xl[i1], xa[i1], xb[i1], xr[i1], s0, s1);
            row_acc(wk[6], wk[7], wk[8], xl[i2], xa[i2], xb[i2], xr[i2], s0, s1);

            const float4 fga = fa[(t + 1) & 1];
            const float4 fgb = fb[(t + 1) & 1];
            const int iy = (t - 2) % 3;   // y row r for the +2y term

            float4 o0, o1;
            o0.x = fmaf(tanh_fast(s0.x), fga.x, 2.f * ya[iy].x);
            o0.y = fmaf(tanh_fast(s0.y), fga.y, 2.f * ya[iy].y);
            o0.z = fmaf(tanh_fast(s0.z), fga.z, 2.f * ya[iy].z);
            o0.w = fmaf(tanh_fast(s0.w), fga.w, 2.f * ya[iy].w);
            o1.x = fmaf(tanh_fast(s1.x), fgb.x, 2.f * yb[iy].x);
            o1.y = fmaf(tanh_fast(s1.y), fgb.y, 2.f * yb[iy].y);
            o1.z = fmaf(tanh_fast(s1.z), fgb.z, 2.f * yb[iy].z);
            o1.w = fmaf(tanh_fast(s1.w), fgb.w, 2.f * yb[iy].w);

            float* po = op + (size_t)r * HW;
            *reinterpret_cast<float4*>(po)     = o0;
            *reinterpret_cast<float4*>(po + 4) = o1;
        }
    }
}

extern "C" void kernel_launch(void* const* d_in, const int* in_sizes, int n_in,
                              void* d_out, int out_size, void* d_ws, size_t ws_size,
                              hipStream_t stream) {
    const float* x = (const float*)d_in[0];
    const float* y = (const float*)d_in[1];
    const float* w = (const float*)d_in[2];
    const float* b = (const float*)d_in[3];
    float* out = (float*)d_out;

    const int planes = in_sizes[0] / (HW * HW);   // B*C = 2048
    dim3 grid(planes);                            // 2048 blocks, 1 plane each
    dim3 block(256);
    fused_gated_dwconv_reg<<<grid, block, 0, stream>>>(x, y, w, b, out);
}

// Round 5
// 99.916 us; speedup vs baseline: 2.3485x; 2.3485x over previous
//
#include <hip/hip_runtime.h>
#include <math.h>

#define HW   128
#define BH   8           // band height (rows per thread)
#define C_CH 256

__device__ __forceinline__ void sig_tanh(float s, float& fg, float& th) {
    float sc = fminf(15.f, fmaxf(-15.f, s));
    float t  = __expf(-sc);                               // e^-s
    fg = __builtin_amdgcn_rcpf(1.f + t);                  // sigmoid
    float t2 = t * t;                                     // e^-2s
    th = (1.f - t2) * __builtin_amdgcn_rcpf(1.f + t2);    // tanh
}

__device__ __forceinline__ float tanh_fast(float s) {
    float sc = fminf(15.f, fmaxf(-15.f, s));
    float t2 = __expf(-2.f * sc);
    return (1.f - t2) * __builtin_amdgcn_rcpf(1.f + t2);
}

// accumulate one stencil row (weights w0,w1,w2) over a 10-wide row {l, a, b, r}
__device__ __forceinline__ void row_acc(float w0, float w1, float w2,
    float l, const float4& a, const float4& b, float r,
    float4& s0, float4& s1)
{
    s0.x = fmaf(w0, l,   fmaf(w1, a.x, fmaf(w2, a.y, s0.x)));
    s0.y = fmaf(w0, a.x, fmaf(w1, a.y, fmaf(w2, a.z, s0.y)));
    s0.z = fmaf(w0, a.y, fmaf(w1, a.z, fmaf(w2, a.w, s0.z)));
    s0.w = fmaf(w0, a.z, fmaf(w1, a.w, fmaf(w2, b.x, s0.w)));
    s1.x = fmaf(w0, a.w, fmaf(w1, b.x, fmaf(w2, b.y, s1.x)));
    s1.y = fmaf(w0, b.x, fmaf(w1, b.y, fmaf(w2, b.z, s1.y)));
    s1.z = fmaf(w0, b.y, fmaf(w1, b.z, fmaf(w2, b.w, s1.z)));
    s1.w = fmaf(w0, b.z, fmaf(w1, b.w, fmaf(w2, r,   s1.w)));
}

// __launch_bounds__(256,4): allocator target <=128 VGPR, natural allocation for
// this body is 64 (R3 evidence) -> HW can still run 8 waves/SIMD. Do NOT use
// (256,8): it clamps to 32 VGPR and spills ~600 MB to scratch (R4 evidence).
__global__ __launch_bounds__(256, 4) void fused_gated_dwconv_reg(
    const float* __restrict__ x, const float* __restrict__ y,
    const float* __restrict__ w, const float* __restrict__ b,
    float* __restrict__ out)
{
    const int tid   = threadIdx.x;
    const int s     = tid & 15;          // col strip (8 cols each)
    const int band  = tid >> 4;          // 16 bands of 8 rows
    const int plane = blockIdx.x;        // one plane per block
    const int c     = plane & (C_CH - 1);
    const int rb    = band * BH;
    const int col0  = s * 8;

    const size_t poff = (size_t)plane * (HW * HW);
    const float* yp = y + poff + col0;
    const float* xp = x + poff + col0;
    float*       op = out + poff + col0;

    float wk[9];
    #pragma unroll
    for (int k = 0; k < 9; ++k) wk[k] = w[c * 9 + k];
    const float bias = b[c];

    // rolling 3-row windows (10 wide: left halo, 8 cols, right halo)
    float  yl[3], yr[3];  float4 ya[3], yb[3];
    float  xl[3], xr[3];  float4 xa[3], xb[3];
    float4 fa[2], fb[2];  // f_gate, 2-row window

    #pragma unroll
    for (int t = 0; t < BH + 4; ++t) {
        // ---- load y row (rb-2+t) into slot t%3, with shuffle halo ----
        {
            int gy = rb - 2 + t;
            bool iny = (unsigned)gy < (unsigned)HW;
            const float* p = yp + (size_t)(iny ? gy : 0) * HW;
            float4 a  = *reinterpret_cast<const float4*>(p);
            float4 bb = *reinterpret_cast<const float4*>(p + 4);
            if (!iny) { a = make_float4(0.f,0.f,0.f,0.f); bb = make_float4(0.f,0.f,0.f,0.f); }
            float l = __shfl_up(bb.w, 1, 16);  if (s == 0)  l = 0.f;
            float r = __shfl_down(a.x, 1, 16); if (s == 15) r = 0.f;
            const int sl = t % 3;
            yl[sl] = l; ya[sl] = a; yb[sl] = bb; yr[sl] = r;
        }
        // ---- compute x_stage row (qx = rb-3+t) into slot t%3 ----
        if (t >= 2) {
            int qx = rb - 3 + t;
            bool inx = (unsigned)qx < (unsigned)HW;
            const float* p = xp + (size_t)(inx ? qx : 0) * HW;
            float4 xva = *reinterpret_cast<const float4*>(p);
            float4 xvb = *reinterpret_cast<const float4*>(p + 4);

            const int i0 = (t - 2) % 3, i1 = (t - 1) % 3, i2 = t % 3;
            float4 s0 = make_float4(bias, bias, bias, bias), s1 = s0;
            row_acc(wk[0], wk[1], wk[2], yl[i0], ya[i0], yb[i0], yr[i0], s0, s1);
            row_acc(wk[3], wk[4], wk[5], yl[i1], ya[i1], yb[i1], yr[i1], s0, s1);
            row_acc(wk[6], wk[7], wk[8], yl[i2], ya[i2], yb[i2], yr[i2], s0, s1);

            float4 fga, fgb, tha, thb;
            sig_tanh(s0.x, fga.x, tha.x);
            sig_tanh(s0.y, fga.y, tha.y);
            sig_tanh(s0.z, fga.z, tha.z);
            sig_tanh(s0.w, fga.w, tha.w);
            sig_tanh(s1.x, fgb.x, thb.x);
            sig_tanh(s1.y, fgb.y, thb.y);
            sig_tanh(s1.z, fgb.z, thb.z);
            sig_tanh(s1.w, fgb.w, thb.w);

            float4 xsa, xsb;
            xsa.x = fga.x * (xva.x + tha.x);
            xsa.y = fga.y * (xva.y + tha.y);
            xsa.z = fga.z * (xva.z + tha.z);
            xsa.w = fga.w * (xva.w + tha.w);
            xsb.x = fgb.x * (xvb.x + thb.x);
            xsb.y = fgb.y * (xvb.y + thb.y);
            xsb.z = fgb.z * (xvb.z + thb.z);
            xsb.w = fgb.w * (xvb.w + thb.w);
            if (!inx) { xsa = make_float4(0.f,0.f,0.f,0.f); xsb = make_float4(0.f,0.f,0.f,0.f); }

            float l = __shfl_up(xsb.w, 1, 16);  if (s == 0)  l = 0.f;
            float r = __shfl_down(xsa.x, 1, 16); if (s == 15) r = 0.f;
            xl[i2] = l; xa[i2] = xsa; xb[i2] = xsb; xr[i2] = r;
            fa[t & 1] = fga; fb[t & 1] = fgb;
        }
        // ---- output row r = rb-4+t ----
        if (t >= 4) {
            int r = rb - 4 + t;
            const int i0 = (t - 2) % 3, i1 = (t - 1) % 3, i2 = t % 3;
            float4 s0 = make_float4(bias, bias, bias, bias), s1 = s0;
            row_acc(wk[0], wk[1], wk[2], xl[i0], xa[i0], xb[i0], xr[i0], s0, s1);
            row_acc(wk[3], wk[4], wk[5], xl[i1], xa[i1], xb[i1], xr[i1], s0, s1);
            row_acc(wk[6], wk[7], wk[8], xl[i2], xa[i2], xb[i2], xr[i2], s0, s1);

            const float4 fga = fa[(t + 1) & 1];
            const float4 fgb = fb[(t + 1) & 1];
            const int iy = (t - 2) % 3;   // y row r for the +2y term

            float4 o0, o1;
            o0.x = fmaf(tanh_fast(s0.x), fga.x, 2.f * ya[iy].x);
            o0.y = fmaf(tanh_fast(s0.y), fga.y, 2.f * ya[iy].y);
            o0.z = fmaf(tanh_fast(s0.z), fga.z, 2.f * ya[iy].z);
            o0.w = fmaf(tanh_fast(s0.w), fga.w, 2.f * ya[iy].w);
            o1.x = fmaf(tanh_fast(s1.x), fgb.x, 2.f * yb[iy].x);
            o1.y = fmaf(tanh_fast(s1.y), fgb.y, 2.f * yb[iy].y);
            o1.z = fmaf(tanh_fast(s1.z), fgb.z, 2.f * yb[iy].z);
            o1.w = fmaf(tanh_fast(s1.w), fgb.w, 2.f * yb[iy].w);

            float* po = op + (size_t)r * HW;
            *reinterpret_cast<float4*>(po)     = o0;
            *reinterpret_cast<float4*>(po + 4) = o1;
        }
    }
}

extern "C" void kernel_launch(void* const* d_in, const int* in_sizes, int n_in,
                              void* d_out, int out_size, void* d_ws, size_t ws_size,
                              hipStream_t stream) {
    const float* x = (const float*)d_in[0];
    const float* y = (const float*)d_in[1];
    const float* w = (const float*)d_in[2];
    const float* b = (const float*)d_in[3];
    float* out = (float*)d_out;

    const int planes = in_sizes[0] / (HW * HW);   // B*C = 2048
    dim3 grid(planes);                            // 2048 blocks, 1 plane each
    dim3 block(256);
    fused_gated_dwconv_reg<<<grid, block, 0, stream>>>(x, y, w, b, out);
}